// Round 1
// 1383.830 us; speedup vs baseline: 1.0190x; 1.0190x over previous
//
#include <hip/hip_runtime.h>

// ---------------------------------------------------------------------------
// ReparamGaussianMoE: D=1024, H=2048, E=8, N=4096, TAU=0.1
// R3: stream-merged expert kernels.
//  - expert_gemm1: z = expert; one A-stage feeds both W1m and W1v MFMA groups
//    (FLOP/LDS-byte 32 -> 43, A fetch halved, barriers per MFMA halved).
//  - gemm2_combine: z = expert; sequential v-GEMM -> in-register transform
//    (acc = eps*exp(0.5*(acc+bv2)) + bm2) -> m-GEMM accumulating on top ->
//    single atomicAdd(out, w*acc). Halves atomics and out RMW traffic,
//    doubles K per block for epilogue amortization.
// ---------------------------------------------------------------------------

typedef _Float16 f16x8 __attribute__((ext_vector_type(8)));
typedef float    f32x4 __attribute__((ext_vector_type(4)));

__device__ __forceinline__ void async_copy16(const void* g, void* l) {
  __builtin_amdgcn_global_load_lds(
      (const __attribute__((address_space(1))) void*)g,
      (__attribute__((address_space(3))) void*)l, 16, 0, 0);
}

// ---- conversion kernels ---------------------------------------------------

__global__ __launch_bounds__(256) void split_x_kernel(
    const float* __restrict__ x, _Float16* __restrict__ Ax) {
  int idx = blockIdx.x * 256 + threadIdx.x;
  int m = idx >> 10, k = idx & 1023;
  float v = x[idx];
  _Float16 hi = (_Float16)v;
  _Float16 lo = (_Float16)(v - (float)hi);
  _Float16* row = Ax + (size_t)m * 3072;
  row[k] = hi;
  row[k + 1024] = hi;
  row[k + 2048] = lo;
}

__global__ __launch_bounds__(256) void split_transpose_wg1_kernel(
    const float* __restrict__ in, _Float16* __restrict__ out) {
  __shared__ float tile[64][65];
  int kb = blockIdx.y * 64, nb = blockIdx.x * 64;
  int c = threadIdx.x & 63, r0 = threadIdx.x >> 6;
#pragma unroll
  for (int i = 0; i < 16; ++i) {
    int r = r0 + i * 4;
    tile[r][c] = in[(size_t)(kb + r) * 2048 + nb + c];
  }
  __syncthreads();
#pragma unroll
  for (int i = 0; i < 16; ++i) {
    int rn = r0 + i * 4;
    float v = tile[c][rn];
    _Float16 hi = (_Float16)v;
    _Float16 lo = (_Float16)(v - (float)hi);
    _Float16* row = out + (size_t)(nb + rn) * 3072 + kb;
    row[c] = hi;
    row[c + 1024] = lo;
    row[c + 2048] = hi;
  }
}

// in [z][K][N] f32 -> out [z][N][K] f16
__global__ __launch_bounds__(256) void transpose_f32_to_f16(
    const float* __restrict__ in, _Float16* __restrict__ out, int K, int N) {
  __shared__ float tile[64][65];
  size_t zo = (size_t)blockIdx.z * K * N;
  int kb = blockIdx.y * 64, nb = blockIdx.x * 64;
  int c = threadIdx.x & 63, r0 = threadIdx.x >> 6;
  const float* ip = in + zo + (size_t)kb * N + nb;
#pragma unroll
  for (int i = 0; i < 16; ++i) {
    int r = r0 + i * 4;
    tile[r][c] = ip[(size_t)r * N + c];
  }
  __syncthreads();
  _Float16* op = out + zo + (size_t)nb * K + kb;
#pragma unroll
  for (int i = 0; i < 16; ++i) {
    int rn = r0 + i * 4;
    op[(size_t)rn * K + c] = (_Float16)tile[c][rn];
  }
}

__global__ __launch_bounds__(256) void zero_out_kernel(float4* __restrict__ p) {
  p[blockIdx.x * 256 + threadIdx.x] = float4{0.f, 0.f, 0.f, 0.f};
}

// ---- gate GEMM: hg = relu(Ax @ Wg1t^T + bg1), 128x128 tile, K=3072 --------
__global__ __launch_bounds__(256) void gate_gemm1_kernel(
    const _Float16* __restrict__ A, const _Float16* __restrict__ Bt,
    float* __restrict__ C, const float* __restrict__ bias) {
  __shared__ _Float16 As[128 * 32];
  __shared__ _Float16 Bs[128 * 32];
  const int tid = threadIdx.x, lane = tid & 63, wid = tid >> 6;
  const int m0 = blockIdx.y * 128, n0 = blockIdx.x * 128;
  const int wm = (wid >> 1) * 64, wn = (wid & 1) * 64;
  const int lanelo = lane & 15, laneq = lane >> 4;
  const int K = 3072, lda = 3072, ldc = 2048;
  f32x4 acc[4][4] = {};

  const int c0 = wid * 128 + lane, c1 = c0 + 64;
  const int ra0 = c0 >> 2, ca0 = (c0 & 3) * 8;
  const int ra1 = c1 >> 2, ca1 = (c1 & 3) * 8;
  _Float16* ldsA0 = As + c0 * 8;
  _Float16* ldsA1 = As + c1 * 8;
  _Float16* ldsB0 = Bs + c0 * 8;
  _Float16* ldsB1 = Bs + c1 * 8;
  const _Float16* Arow0 = A + (size_t)(m0 + ra0) * lda + ca0;
  const _Float16* Arow1 = A + (size_t)(m0 + ra1) * lda + ca1;
  const _Float16* Brow0 = Bt + (size_t)(n0 + ra0) * K + ca0;
  const _Float16* Brow1 = Bt + (size_t)(n0 + ra1) * K + ca1;

  for (int k0 = 0; k0 < K; k0 += 32) {
    async_copy16(Arow0 + k0, ldsA0);
    async_copy16(Arow1 + k0, ldsA1);
    async_copy16(Brow0 + k0, ldsB0);
    async_copy16(Brow1 + k0, ldsB1);
    __syncthreads();
    f16x8 a[4], b[4];
#pragma unroll
    for (int i = 0; i < 4; ++i)
      a[i] = *reinterpret_cast<const f16x8*>(
          &As[(wm + i * 16 + lanelo) * 32 + laneq * 8]);
#pragma unroll
    for (int j = 0; j < 4; ++j)
      b[j] = *reinterpret_cast<const f16x8*>(
          &Bs[(wn + j * 16 + lanelo) * 32 + laneq * 8]);
#pragma unroll
    for (int i = 0; i < 4; ++i)
#pragma unroll
      for (int j = 0; j < 4; ++j)
        acc[i][j] =
            __builtin_amdgcn_mfma_f32_16x16x32_f16(a[i], b[j], acc[i][j], 0, 0, 0);
    __syncthreads();
  }

#pragma unroll
  for (int j = 0; j < 4; ++j) {
    const int n = n0 + wn + j * 16 + lanelo;
    const float bn = bias[n];
#pragma unroll
    for (int i = 0; i < 4; ++i) {
#pragma unroll
      for (int r = 0; r < 4; ++r) {
        const int m = m0 + wm + i * 16 + laneq * 4 + r;
        float v = acc[i][j][r] + bn;
        C[(size_t)m * ldc + n] = v > 0.f ? v : 0.f;
      }
    }
  }
}

// ---- expert GEMM1, stream-merged: z = expert, one A-stage feeds both ------
// hm = relu(x@Wm1+bm1), hv = relu(x@Wv1+bv1)
__global__ __launch_bounds__(256, 2) void expert_gemm1_kernel(
    const _Float16* __restrict__ A, const _Float16* __restrict__ W1t,
    _Float16* __restrict__ hm, _Float16* __restrict__ hv,
    const float* __restrict__ bm1, const float* __restrict__ bv1) {
  __shared__ _Float16 As[128 * 32];
  __shared__ _Float16 Bms[128 * 32];
  __shared__ _Float16 Bvs[128 * 32];
  const int tid = threadIdx.x, lane = tid & 63, wid = tid >> 6;
  const int e = blockIdx.z;
  const _Float16* __restrict__ Btm = W1t + (size_t)e * 2048 * 1024;
  const _Float16* __restrict__ Btv = W1t + (size_t)(8 + e) * 2048 * 1024;
  _Float16* __restrict__ Cm = hm + (size_t)e * 4096 * 2048;
  _Float16* __restrict__ Cv = hv + (size_t)e * 4096 * 2048;
  const float* __restrict__ bm = bm1 + e * 2048;
  const float* __restrict__ bv = bv1 + e * 2048;
  const int m0 = blockIdx.y * 128, n0 = blockIdx.x * 128;
  const int wm = (wid >> 1) * 64, wn = (wid & 1) * 64;
  const int lanelo = lane & 15, laneq = lane >> 4;
  const int K = 1024, lda = 3072, ldc = 2048;
  f32x4 accm[4][4] = {};
  f32x4 accv[4][4] = {};

  const int c0 = wid * 128 + lane, c1 = c0 + 64;
  const int ra0 = c0 >> 2, ca0 = (c0 & 3) * 8;
  const int ra1 = c1 >> 2, ca1 = (c1 & 3) * 8;
  _Float16* ldsA0 = As + c0 * 8;
  _Float16* ldsA1 = As + c1 * 8;
  _Float16* ldsBm0 = Bms + c0 * 8;
  _Float16* ldsBm1 = Bms + c1 * 8;
  _Float16* ldsBv0 = Bvs + c0 * 8;
  _Float16* ldsBv1 = Bvs + c1 * 8;
  const _Float16* Arow0 = A + (size_t)(m0 + ra0) * lda + ca0;
  const _Float16* Arow1 = A + (size_t)(m0 + ra1) * lda + ca1;
  const _Float16* Bmrow0 = Btm + (size_t)(n0 + ra0) * K + ca0;
  const _Float16* Bmrow1 = Btm + (size_t)(n0 + ra1) * K + ca1;
  const _Float16* Bvrow0 = Btv + (size_t)(n0 + ra0) * K + ca0;
  const _Float16* Bvrow1 = Btv + (size_t)(n0 + ra1) * K + ca1;

  for (int k0 = 0; k0 < K; k0 += 32) {
    async_copy16(Arow0 + k0, ldsA0);
    async_copy16(Arow1 + k0, ldsA1);
    async_copy16(Bmrow0 + k0, ldsBm0);
    async_copy16(Bmrow1 + k0, ldsBm1);
    async_copy16(Bvrow0 + k0, ldsBv0);
    async_copy16(Bvrow1 + k0, ldsBv1);
    __syncthreads();
    f16x8 a[4], b[4];
#pragma unroll
    for (int i = 0; i < 4; ++i)
      a[i] = *reinterpret_cast<const f16x8*>(
          &As[(wm + i * 16 + lanelo) * 32 + laneq * 8]);
#pragma unroll
    for (int j = 0; j < 4; ++j)
      b[j] = *reinterpret_cast<const f16x8*>(
          &Bms[(wn + j * 16 + lanelo) * 32 + laneq * 8]);
#pragma unroll
    for (int i = 0; i < 4; ++i)
#pragma unroll
      for (int j = 0; j < 4; ++j)
        accm[i][j] =
            __builtin_amdgcn_mfma_f32_16x16x32_f16(a[i], b[j], accm[i][j], 0, 0, 0);
#pragma unroll
    for (int j = 0; j < 4; ++j)
      b[j] = *reinterpret_cast<const f16x8*>(
          &Bvs[(wn + j * 16 + lanelo) * 32 + laneq * 8]);
#pragma unroll
    for (int i = 0; i < 4; ++i)
#pragma unroll
      for (int j = 0; j < 4; ++j)
        accv[i][j] =
            __builtin_amdgcn_mfma_f32_16x16x32_f16(a[i], b[j], accv[i][j], 0, 0, 0);
    __syncthreads();
  }

#pragma unroll
  for (int j = 0; j < 4; ++j) {
    const int n = n0 + wn + j * 16 + lanelo;
    const float bmn = bm[n], bvn = bv[n];
#pragma unroll
    for (int i = 0; i < 4; ++i) {
#pragma unroll
      for (int r = 0; r < 4; ++r) {
        const int m = m0 + wm + i * 16 + laneq * 4 + r;
        float vm = accm[i][j][r] + bmn;
        float vv = accv[i][j][r] + bvn;
        Cm[(size_t)m * ldc + n] = (_Float16)(vm > 0.f ? vm : 0.f);
        Cv[(size_t)m * ldc + n] = (_Float16)(vv > 0.f ? vv : 0.f);
      }
    }
  }
}

// ---- GEMM2 + combine, stream-merged: z = expert ---------------------------
// pass 1 (v): acc = hv@Wv2          -> acc = eps*exp(0.5*(acc+bv2)) + bm2
// pass 2 (m): acc += hm@Wm2         -> out += w * acc   (one atomic per elem)
__global__ __launch_bounds__(256) void gemm2_combine_kernel(
    const _Float16* __restrict__ hm, const _Float16* __restrict__ hv,
    const _Float16* __restrict__ W2t, const float* __restrict__ bm2,
    const float* __restrict__ bv2, const float* __restrict__ eps,
    const float* __restrict__ w, float* __restrict__ out) {
  __shared__ _Float16 As[128 * 32];
  __shared__ _Float16 Bs[128 * 32];
  const int tid = threadIdx.x, lane = tid & 63, wid = tid >> 6;
  const int e = blockIdx.z;
  const _Float16* __restrict__ Am = hm + (size_t)e * 4096 * 2048;
  const _Float16* __restrict__ Av = hv + (size_t)e * 4096 * 2048;
  const _Float16* __restrict__ Btm = W2t + (size_t)e * 1024 * 2048;
  const _Float16* __restrict__ Btv = W2t + (size_t)(8 + e) * 1024 * 2048;
  const float* __restrict__ bmb = bm2 + e * 1024;
  const float* __restrict__ bvb = bv2 + e * 1024;
  const int m0 = blockIdx.y * 128, n0 = blockIdx.x * 128;
  const int wm = (wid >> 1) * 64, wn = (wid & 1) * 64;
  const int lanelo = lane & 15, laneq = lane >> 4;
  const int K = 2048, lda = 2048;
  f32x4 acc[4][4] = {};

  const int c0 = wid * 128 + lane, c1 = c0 + 64;
  const int ra0 = c0 >> 2, ca0 = (c0 & 3) * 8;
  const int ra1 = c1 >> 2, ca1 = (c1 & 3) * 8;
  _Float16* ldsA0 = As + c0 * 8;
  _Float16* ldsA1 = As + c1 * 8;
  _Float16* ldsB0 = Bs + c0 * 8;
  _Float16* ldsB1 = Bs + c1 * 8;
  const size_t aoff0 = (size_t)(m0 + ra0) * lda + ca0;
  const size_t aoff1 = (size_t)(m0 + ra1) * lda + ca1;
  const size_t boff0 = (size_t)(n0 + ra0) * K + ca0;
  const size_t boff1 = (size_t)(n0 + ra1) * K + ca1;

  // ---- pass 1: logvar GEMM (A=hv, B=Wv2) ----
  {
    const _Float16* Arow0 = Av + aoff0;
    const _Float16* Arow1 = Av + aoff1;
    const _Float16* Brow0 = Btv + boff0;
    const _Float16* Brow1 = Btv + boff1;
    for (int k0 = 0; k0 < K; k0 += 32) {
      async_copy16(Arow0 + k0, ldsA0);
      async_copy16(Arow1 + k0, ldsA1);
      async_copy16(Brow0 + k0, ldsB0);
      async_copy16(Brow1 + k0, ldsB1);
      __syncthreads();
      f16x8 a[4], b[4];
#pragma unroll
      for (int i = 0; i < 4; ++i)
        a[i] = *reinterpret_cast<const f16x8*>(
            &As[(wm + i * 16 + lanelo) * 32 + laneq * 8]);
#pragma unroll
      for (int j = 0; j < 4; ++j)
        b[j] = *reinterpret_cast<const f16x8*>(
            &Bs[(wn + j * 16 + lanelo) * 32 + laneq * 8]);
#pragma unroll
      for (int i = 0; i < 4; ++i)
#pragma unroll
        for (int j = 0; j < 4; ++j)
          acc[i][j] =
              __builtin_amdgcn_mfma_f32_16x16x32_f16(a[i], b[j], acc[i][j], 0, 0, 0);
      __syncthreads();
    }
  }

  // ---- in-register transform: acc = eps*exp(0.5*(acc+bv2)) + bm2 ----
#pragma unroll
  for (int j = 0; j < 4; ++j) {
    const int d = n0 + wn + j * 16 + lanelo;
    const float bvd = bvb[d];
    const float bmd = bmb[d];
#pragma unroll
    for (int i = 0; i < 4; ++i) {
#pragma unroll
      for (int r = 0; r < 4; ++r) {
        const int m = m0 + wm + i * 16 + laneq * 4 + r;
        const float ev = eps[(size_t)m * 8192 + e * 1024 + d];
        acc[i][j][r] = ev * __expf(0.5f * (acc[i][j][r] + bvd)) + bmd;
      }
    }
  }

  // ---- pass 2: mu GEMM (A=hm, B=Wm2), accumulating on top of acc ----
  {
    const _Float16* Arow0 = Am + aoff0;
    const _Float16* Arow1 = Am + aoff1;
    const _Float16* Brow0 = Btm + boff0;
    const _Float16* Brow1 = Btm + boff1;
    for (int k0 = 0; k0 < K; k0 += 32) {
      async_copy16(Arow0 + k0, ldsA0);
      async_copy16(Arow1 + k0, ldsA1);
      async_copy16(Brow0 + k0, ldsB0);
      async_copy16(Brow1 + k0, ldsB1);
      __syncthreads();
      f16x8 a[4], b[4];
#pragma unroll
      for (int i = 0; i < 4; ++i)
        a[i] = *reinterpret_cast<const f16x8*>(
            &As[(wm + i * 16 + lanelo) * 32 + laneq * 8]);
#pragma unroll
      for (int j = 0; j < 4; ++j)
        b[j] = *reinterpret_cast<const f16x8*>(
            &Bs[(wn + j * 16 + lanelo) * 32 + laneq * 8]);
#pragma unroll
      for (int i = 0; i < 4; ++i)
#pragma unroll
        for (int j = 0; j < 4; ++j)
          acc[i][j] =
              __builtin_amdgcn_mfma_f32_16x16x32_f16(a[i], b[j], acc[i][j], 0, 0, 0);
      __syncthreads();
    }
  }

  // ---- epilogue: out += w * (mu + eps*exp(0.5*lv)), one atomic each ----
#pragma unroll
  for (int i = 0; i < 4; ++i) {
#pragma unroll
    for (int r = 0; r < 4; ++r) {
      const int m = m0 + wm + i * 16 + laneq * 4 + r;
      const float wgt = w[(size_t)m * 8 + e];
      float* orow = out + (size_t)m * 1024;
#pragma unroll
      for (int j = 0; j < 4; ++j) {
        const int d = n0 + wn + j * 16 + lanelo;
        unsafeAtomicAdd(&orow[d], wgt * acc[i][j][r]);
      }
    }
  }
}

// ---- gate finish ----------------------------------------------------------
__global__ __launch_bounds__(256) void gate_finish_kernel(
    const float* __restrict__ hg, const float* __restrict__ Wg2,
    const float* __restrict__ bg2, const float* __restrict__ gu,
    float* __restrict__ w) {
  const int lane = threadIdx.x & 63, wid = threadIdx.x >> 6;
  const int row = blockIdx.x * 4 + wid;
  const float* hrow = hg + (size_t)row * 2048;
  float acc[8] = {0.f, 0.f, 0.f, 0.f, 0.f, 0.f, 0.f, 0.f};
  for (int h = lane; h < 2048; h += 64) {
    const float hv = hrow[h];
    const float* wr = Wg2 + (size_t)h * 8;
#pragma unroll
    for (int e = 0; e < 8; ++e) acc[e] += hv * wr[e];
  }
#pragma unroll
  for (int off = 32; off > 0; off >>= 1) {
#pragma unroll
    for (int e = 0; e < 8; ++e) acc[e] += __shfl_down(acc[e], off);
  }
  if (lane == 0) {
    float z[8], zmax = -1e30f;
#pragma unroll
    for (int e = 0; e < 8; ++e) {
      const float u = gu[(size_t)row * 8 + e];
      const float g = -logf(-logf(u));
      z[e] = (acc[e] + bg2[e] + g) / 0.1f;
      zmax = fmaxf(zmax, z[e]);
    }
    float s = 0.f;
#pragma unroll
    for (int e = 0; e < 8; ++e) {
      z[e] = __expf(z[e] - zmax);
      s += z[e];
    }
    const float inv = 1.f / s;
#pragma unroll
    for (int e = 0; e < 8; ++e) w[(size_t)row * 8 + e] = z[e] * inv;
  }
}

// ---------------------------------------------------------------------------

extern "C" void kernel_launch(void* const* d_in, const int* in_sizes, int n_in,
                              void* d_out, int out_size, void* d_ws,
                              size_t ws_size, hipStream_t stream) {
  const float* x = (const float*)d_in[0];
  const float* gu = (const float*)d_in[1];
  const float* eps = (const float*)d_in[2];
  const float* Wg1 = (const float*)d_in[3];
  const float* bg1 = (const float*)d_in[4];
  const float* Wg2 = (const float*)d_in[5];
  const float* bg2 = (const float*)d_in[6];
  const float* Wm1 = (const float*)d_in[7];
  const float* bm1 = (const float*)d_in[8];
  const float* Wm2 = (const float*)d_in[9];
  const float* bm2 = (const float*)d_in[10];
  const float* Wv1 = (const float*)d_in[11];
  const float* bv1 = (const float*)d_in[12];
  const float* Wv2 = (const float*)d_in[13];
  const float* bv2 = (const float*)d_in[14];
  float* out = (float*)d_out;

  char* ws = (char*)d_ws;
  size_t off = 0;
  auto alloc = [&](size_t bytes) -> void* {
    void* p = ws + off;
    off = (off + bytes + 255) & ~(size_t)255;
    return p;
  };
  _Float16* Ax = (_Float16*)alloc(4096UL * 3072 * 2);        // 24 MB
  _Float16* Wg1t = (_Float16*)alloc(2048UL * 3072 * 2);      // 12 MB
  _Float16* W1t = (_Float16*)alloc(16UL * 2048 * 1024 * 2);  // 64 MB
  _Float16* W2t = (_Float16*)alloc(16UL * 1024 * 2048 * 2);  // 64 MB
  float* hg = (float*)alloc(4096UL * 2048 * 4);              // 32 MB
  float* wbuf = (float*)alloc(4096UL * 8 * 4);
  _Float16* hm = (_Float16*)alloc(8UL * 4096 * 2048 * 2);    // 128 MB
  _Float16* hv = (_Float16*)alloc(8UL * 4096 * 2048 * 2);    // 128 MB

  // 1) conversions + out zero-init
  zero_out_kernel<<<4096, 256, 0, stream>>>((float4*)out);
  split_x_kernel<<<4096 * 1024 / 256, 256, 0, stream>>>(x, Ax);
  split_transpose_wg1_kernel<<<dim3(2048 / 64, 1024 / 64), 256, 0, stream>>>(Wg1, Wg1t);
  transpose_f32_to_f16<<<dim3(2048 / 64, 1024 / 64, 8), 256, 0, stream>>>(
      Wm1, W1t, 1024, 2048);
  transpose_f32_to_f16<<<dim3(2048 / 64, 1024 / 64, 8), 256, 0, stream>>>(
      Wv1, W1t + 8UL * 2048 * 1024, 1024, 2048);
  transpose_f32_to_f16<<<dim3(1024 / 64, 2048 / 64, 8), 256, 0, stream>>>(
      Wm2, W2t, 2048, 1024);
  transpose_f32_to_f16<<<dim3(1024 / 64, 2048 / 64, 8), 256, 0, stream>>>(
      Wv2, W2t + 8UL * 1024 * 2048, 2048, 1024);

  // 2) gate
  gate_gemm1_kernel<<<dim3(2048 / 128, 4096 / 128), 256, 0, stream>>>(
      Ax, Wg1t, hg, bg1);
  gate_finish_kernel<<<4096 / 4, 256, 0, stream>>>(hg, Wg2, bg2, gu, wbuf);

  // 3) experts: stream-merged GEMM1, stream-merged GEMM2+combine
  expert_gemm1_kernel<<<dim3(2048 / 128, 4096 / 128, 8), 256, 0, stream>>>(
      Ax, W1t, hm, hv, bm1, bv1);
  gemm2_combine_kernel<<<dim3(1024 / 128, 4096 / 128, 8), 256, 0, stream>>>(
      hm, hv, W2t, bm2, bv2, eps, wbuf, out);
}

// Round 2
// 1170.458 us; speedup vs baseline: 1.2048x; 1.1823x over previous
//
#include <hip/hip_runtime.h>

// ---------------------------------------------------------------------------
// ReparamGaussianMoE: D=1024, H=2048, E=8, N=4096, TAU=0.1
// R4: all big GEMMs ported to a shared 256x256 (BK=64) 8-phase pipelined core
// (T3+T4 counted vmcnt, T2 LDS XOR-swizzle via pre-swizzled global source,
//  T5 setprio). gemm2 keeps the sequential v->transform->m accumulation with
// a single atomicAdd epilogue.
// ---------------------------------------------------------------------------

typedef _Float16 f16x8 __attribute__((ext_vector_type(8)));
typedef float    f32x4 __attribute__((ext_vector_type(4)));

__device__ __forceinline__ void async_copy16(const void* g, void* l) {
  __builtin_amdgcn_global_load_lds(
      (const __attribute__((address_space(1))) void*)g,
      (__attribute__((address_space(3))) void*)l, 16, 0, 0);
}

#define MFMA16(a_, b_, c_) __builtin_amdgcn_mfma_f32_16x16x32_f16(a_, b_, c_, 0, 0, 0)

// ---- conversion kernels ---------------------------------------------------

__global__ __launch_bounds__(256) void split_x_kernel(
    const float* __restrict__ x, _Float16* __restrict__ Ax) {
  int idx = blockIdx.x * 256 + threadIdx.x;
  int m = idx >> 10, k = idx & 1023;
  float v = x[idx];
  _Float16 hi = (_Float16)v;
  _Float16 lo = (_Float16)(v - (float)hi);
  _Float16* row = Ax + (size_t)m * 3072;
  row[k] = hi;
  row[k + 1024] = hi;
  row[k + 2048] = lo;
}

__global__ __launch_bounds__(256) void split_transpose_wg1_kernel(
    const float* __restrict__ in, _Float16* __restrict__ out) {
  __shared__ float tile[64][65];
  int kb = blockIdx.y * 64, nb = blockIdx.x * 64;
  int c = threadIdx.x & 63, r0 = threadIdx.x >> 6;
#pragma unroll
  for (int i = 0; i < 16; ++i) {
    int r = r0 + i * 4;
    tile[r][c] = in[(size_t)(kb + r) * 2048 + nb + c];
  }
  __syncthreads();
#pragma unroll
  for (int i = 0; i < 16; ++i) {
    int rn = r0 + i * 4;
    float v = tile[c][rn];
    _Float16 hi = (_Float16)v;
    _Float16 lo = (_Float16)(v - (float)hi);
    _Float16* row = out + (size_t)(nb + rn) * 3072 + kb;
    row[c] = hi;
    row[c + 1024] = lo;
    row[c + 2048] = hi;
  }
}

// in [z][K][N] f32 -> out [z][N][K] f16
__global__ __launch_bounds__(256) void transpose_f32_to_f16(
    const float* __restrict__ in, _Float16* __restrict__ out, int K, int N) {
  __shared__ float tile[64][65];
  size_t zo = (size_t)blockIdx.z * K * N;
  int kb = blockIdx.y * 64, nb = blockIdx.x * 64;
  int c = threadIdx.x & 63, r0 = threadIdx.x >> 6;
  const float* ip = in + zo + (size_t)kb * N + nb;
#pragma unroll
  for (int i = 0; i < 16; ++i) {
    int r = r0 + i * 4;
    tile[r][c] = ip[(size_t)r * N + c];
  }
  __syncthreads();
  _Float16* op = out + zo + (size_t)nb * K + kb;
#pragma unroll
  for (int i = 0; i < 16; ++i) {
    int rn = r0 + i * 4;
    op[(size_t)rn * K + c] = (_Float16)tile[c][rn];
  }
}

__global__ __launch_bounds__(256) void zero_out_kernel(float4* __restrict__ p) {
  p[blockIdx.x * 256 + threadIdx.x] = float4{0.f, 0.f, 0.f, 0.f};
}

// ---------------------------------------------------------------------------
// 256x256 tile, BK=64, 8 waves (2M x 4N), double-buffered 128 KiB LDS,
// 8-phase schedule with counted vmcnt. Accumulates into acc[8][4] (f32x4).
//
// LDS swizzle: logical f16 (row, c) stored at f16 index row*64 + (c ^
// ((row&7)<<3)). global_load_lds writes linearly, so the *source* address is
// inverse-permuted per thread; ds_reads apply the same XOR. 16 lanes reading
// 16 consecutive rows at one 16B column then spread uniformly over all 32
// banks (2 lanes / 4-bank slot = free).
//
// Staging schedule (race-free by retirement analysis):
//   phase1: read a[m0-3], b[n0-1]; issue A(kt+1,h0) -> other buffer
//   phase2: read b[n2-3];          issue A(kt+1,h1) -> other buffer
//   phase3: read a[m4-7];          issue B(kt+2,h0) -> CURRENT buffer
//            (all B reads of tile kt retired at phase-2 closing barrier)
//   phase4: (regs only)            issue B(kt+2,h1) -> CURRENT buffer
//   tile end: s_waitcnt vmcnt(4) (B(kt+2) may stay in flight) BEFORE the
//   closing barrier, so every wave's staged data is landed for all waves.
// ---------------------------------------------------------------------------
__device__ __forceinline__ void gemm256_acc(
    const _Float16* __restrict__ Abase, const int lda,
    const _Float16* __restrict__ Bbase, const int ldb,
    const int NT, _Float16* lds, f32x4 (&acc)[8][4]) {
  const int tid = threadIdx.x;
  const int lane = tid & 63, wid = tid >> 6;
  const int wm = wid >> 2, wn = wid & 3;
  const int lanelo = lane & 15, laneq = lane >> 4;
  const int colp0 = (laneq * 8) ^ ((lanelo & 7) << 3);
  const int rowoffA = (wm * 128 + lanelo) * 64;
  const int rowoffB = (wn * 64 + lanelo) * 64;

  _Float16* const As0 = lds;
  _Float16* const As1 = lds + 16384;
  _Float16* const Bs0 = lds + 32768;
  _Float16* const Bs1 = lds + 49152;

  // staging: thread t handles logical row s*64 + (t>>3), col 8*((t&7)^((t>>3)&7))
  const int sr = tid >> 3;
  const int sc = ((tid & 7) ^ (sr & 7)) << 3;
  const size_t goffA = (size_t)sr * lda + sc;
  const size_t goffB = (size_t)sr * ldb + sc;
  const size_t rowsA64 = (size_t)64 * lda;
  const size_t rowsB64 = (size_t)64 * ldb;
  const int tid8 = tid * 8;

#define STAGE_A(dstbuf, kp, hf)                                  \
  do {                                                           \
    const _Float16* g_ = (kp) + (size_t)(hf)*2 * rowsA64 + goffA;\
    _Float16* d_ = (dstbuf) + (hf)*8192 + tid8;                  \
    async_copy16(g_, d_);                                        \
    async_copy16(g_ + rowsA64, d_ + 4096);                       \
  } while (0)
#define STAGE_B(dstbuf, kp, hf)                                  \
  do {                                                           \
    const _Float16* g_ = (kp) + (size_t)(hf)*2 * rowsB64 + goffB;\
    _Float16* d_ = (dstbuf) + (hf)*8192 + tid8;                  \
    async_copy16(g_, d_);                                        \
    async_copy16(g_ + rowsB64, d_ + 4096);                       \
  } while (0)
#define BARRIER() asm volatile("s_barrier" ::: "memory")

  const _Float16* aN = Abase + 64;   // k-base of tile kt+1
  const _Float16* bN = Bbase + 128;  // k-base of tile kt+2

  // prologue: tile0 A+B -> buf0, tile1 B -> buf1 (12 loads/wave)
  STAGE_A(As0, Abase, 0);
  STAGE_A(As0, Abase, 1);
  STAGE_B(Bs0, Bbase, 0);
  STAGE_B(Bs0, Bbase, 1);
  STAGE_B(Bs1, Bbase + 64, 0);
  STAGE_B(Bs1, Bbase + 64, 1);
  asm volatile("s_waitcnt vmcnt(4)" ::: "memory");  // tile0 landed
  BARRIER();

  for (int kt = 0; kt < NT; ++kt) {
    _Float16* const bufA = (kt & 1) ? As1 : As0;
    _Float16* const bufB = (kt & 1) ? Bs1 : Bs0;
    _Float16* const nxtA = (kt & 1) ? As0 : As1;
    const _Float16* const rA0 = bufA + rowoffA + colp0;
    const _Float16* const rA1 = bufA + rowoffA + (colp0 ^ 32);
    const _Float16* const rB0 = bufB + rowoffB + colp0;
    const _Float16* const rB1 = bufB + rowoffB + (colp0 ^ 32);
    const bool st1 = (kt + 1 < NT), st2 = (kt + 2 < NT);
    f16x8 a[4][2], b[4][2];

    // ---------------- phase 1: m0-3 x n0-1 ----------------
#pragma unroll
    for (int i = 0; i < 4; ++i) {
      a[i][0] = *(const f16x8*)(rA0 + i * 1024);
      a[i][1] = *(const f16x8*)(rA1 + i * 1024);
    }
#pragma unroll
    for (int j = 0; j < 2; ++j) {
      b[j][0] = *(const f16x8*)(rB0 + j * 1024);
      b[j][1] = *(const f16x8*)(rB1 + j * 1024);
    }
    if (st1) STAGE_A(nxtA, aN, 0);
    BARRIER();
    __builtin_amdgcn_sched_barrier(0);
    __builtin_amdgcn_s_setprio(1);
#pragma unroll
    for (int i = 0; i < 4; ++i)
#pragma unroll
      for (int j = 0; j < 2; ++j) {
        acc[i][j] = MFMA16(a[i][0], b[j][0], acc[i][j]);
        acc[i][j] = MFMA16(a[i][1], b[j][1], acc[i][j]);
      }
    __builtin_amdgcn_s_setprio(0);
    __builtin_amdgcn_sched_barrier(0);
    BARRIER();

    // ---------------- phase 2: m0-3 x n2-3 ----------------
#pragma unroll
    for (int j = 0; j < 2; ++j) {
      b[2 + j][0] = *(const f16x8*)(rB0 + (2 + j) * 1024);
      b[2 + j][1] = *(const f16x8*)(rB1 + (2 + j) * 1024);
    }
    if (st1) STAGE_A(nxtA, aN, 1);
    BARRIER();
    __builtin_amdgcn_sched_barrier(0);
    __builtin_amdgcn_s_setprio(1);
#pragma unroll
    for (int i = 0; i < 4; ++i)
#pragma unroll
      for (int j = 0; j < 2; ++j) {
        acc[i][2 + j] = MFMA16(a[i][0], b[2 + j][0], acc[i][2 + j]);
        acc[i][2 + j] = MFMA16(a[i][1], b[2 + j][1], acc[i][2 + j]);
      }
    __builtin_amdgcn_s_setprio(0);
    __builtin_amdgcn_sched_barrier(0);
    BARRIER();

    // ---------------- phase 3: m4-7 x n0-1 ----------------
#pragma unroll
    for (int i = 0; i < 4; ++i) {
      a[i][0] = *(const f16x8*)(rA0 + 4096 + i * 1024);
      a[i][1] = *(const f16x8*)(rA1 + 4096 + i * 1024);
    }
    if (st2) STAGE_B(bufB, bN, 0);
    BARRIER();
    __builtin_amdgcn_sched_barrier(0);
    __builtin_amdgcn_s_setprio(1);
#pragma unroll
    for (int i = 0; i < 4; ++i)
#pragma unroll
      for (int j = 0; j < 2; ++j) {
        acc[4 + i][j] = MFMA16(a[i][0], b[j][0], acc[4 + i][j]);
        acc[4 + i][j] = MFMA16(a[i][1], b[j][1], acc[4 + i][j]);
      }
    __builtin_amdgcn_s_setprio(0);
    __builtin_amdgcn_sched_barrier(0);
    BARRIER();

    // ---------------- phase 4: m4-7 x n2-3 ----------------
    if (st2) STAGE_B(bufB, bN, 1);
    BARRIER();
    __builtin_amdgcn_sched_barrier(0);
    __builtin_amdgcn_s_setprio(1);
#pragma unroll
    for (int i = 0; i < 4; ++i)
#pragma unroll
      for (int j = 0; j < 2; ++j) {
        acc[4 + i][2 + j] = MFMA16(a[i][0], b[2 + j][0], acc[4 + i][2 + j]);
        acc[4 + i][2 + j] = MFMA16(a[i][1], b[2 + j][1], acc[4 + i][2 + j]);
      }
    __builtin_amdgcn_s_setprio(0);
    __builtin_amdgcn_sched_barrier(0);
    // tile boundary: wait for tile kt+1's data (B(kt+2) may stay in flight),
    // THEN barrier so every wave's staged data is visible to all waves.
    if (st2) {
      asm volatile("s_waitcnt vmcnt(4)" ::: "memory");
    } else {
      asm volatile("s_waitcnt vmcnt(0)" ::: "memory");
    }
    BARRIER();

    aN += 64;
    bN += 64;
  }
#undef STAGE_A
#undef STAGE_B
#undef BARRIER
}

// ---- gate GEMM1: hg = relu(Ax @ Wg1t^T + bg1), f32 out --------------------
__global__ __launch_bounds__(512, 2) void gate_gemm1_256(
    const _Float16* __restrict__ A, const _Float16* __restrict__ Bt,
    float* __restrict__ C, const float* __restrict__ bias) {
  extern __shared__ _Float16 lds[];
  const int m0 = blockIdx.y * 256, n0 = blockIdx.x * 256;
  f32x4 acc[8][4] = {};
  gemm256_acc(A + (size_t)m0 * 3072, 3072, Bt + (size_t)n0 * 3072, 3072, 48,
              lds, acc);
  const int tid = threadIdx.x, lane = tid & 63, wid = tid >> 6;
  const int wm = wid >> 2, wn = wid & 3;
  const int lanelo = lane & 15, laneq = lane >> 4;
#pragma unroll
  for (int nf = 0; nf < 4; ++nf) {
    const int n = n0 + wn * 64 + nf * 16 + lanelo;
    const float bn = bias[n];
#pragma unroll
    for (int mf = 0; mf < 8; ++mf)
#pragma unroll
      for (int r = 0; r < 4; ++r) {
        const int m = m0 + wm * 128 + mf * 16 + laneq * 4 + r;
        float v = acc[mf][nf][r] + bn;
        C[(size_t)m * 2048 + n] = v > 0.f ? v : 0.f;
      }
  }
}

// ---- expert GEMM1: z = s*8+e; h = relu(x @ W1^T + b1), f16 out ------------
__global__ __launch_bounds__(512, 2) void expert_gemm1_256(
    const _Float16* __restrict__ A, const _Float16* __restrict__ W1t,
    _Float16* __restrict__ hm, _Float16* __restrict__ hv,
    const float* __restrict__ bm1, const float* __restrict__ bv1) {
  extern __shared__ _Float16 lds[];
  const int z = blockIdx.z, e = z & 7, s = z >> 3;
  const _Float16* __restrict__ Bt = W1t + (size_t)z * 2048 * 1024;
  _Float16* __restrict__ C = (s ? hv : hm) + (size_t)e * 4096 * 2048;
  const float* __restrict__ bias = (s ? bv1 : bm1) + e * 2048;
  const int m0 = blockIdx.y * 256, n0 = blockIdx.x * 256;
  f32x4 acc[8][4] = {};
  gemm256_acc(A + (size_t)m0 * 3072, 3072, Bt + (size_t)n0 * 1024, 1024, 16,
              lds, acc);
  const int tid = threadIdx.x, lane = tid & 63, wid = tid >> 6;
  const int wm = wid >> 2, wn = wid & 3;
  const int lanelo = lane & 15, laneq = lane >> 4;
#pragma unroll
  for (int nf = 0; nf < 4; ++nf) {
    const int n = n0 + wn * 64 + nf * 16 + lanelo;
    const float bn = bias[n];
#pragma unroll
    for (int mf = 0; mf < 8; ++mf)
#pragma unroll
      for (int r = 0; r < 4; ++r) {
        const int m = m0 + wm * 128 + mf * 16 + laneq * 4 + r;
        float v = acc[mf][nf][r] + bn;
        C[(size_t)m * 2048 + n] = (_Float16)(v > 0.f ? v : 0.f);
      }
  }
}

// ---- GEMM2 + combine: z = expert; v-pass -> reparam transform -> m-pass ---
__global__ __launch_bounds__(512, 2) void gemm2_combine_256(
    const _Float16* __restrict__ hm, const _Float16* __restrict__ hv,
    const _Float16* __restrict__ W2t, const float* __restrict__ bm2,
    const float* __restrict__ bv2, const float* __restrict__ eps,
    const float* __restrict__ w, float* __restrict__ out) {
  extern __shared__ _Float16 lds[];
  const int e = blockIdx.z;
  const _Float16* __restrict__ Am = hm + (size_t)e * 4096 * 2048;
  const _Float16* __restrict__ Av = hv + (size_t)e * 4096 * 2048;
  const _Float16* __restrict__ Btm = W2t + (size_t)e * 1024 * 2048;
  const _Float16* __restrict__ Btv = W2t + (size_t)(8 + e) * 1024 * 2048;
  const float* __restrict__ bmb = bm2 + e * 1024;
  const float* __restrict__ bvb = bv2 + e * 1024;
  const int m0 = blockIdx.y * 256, n0 = blockIdx.x * 256;
  const int tid = threadIdx.x, lane = tid & 63, wid = tid >> 6;
  const int wm = wid >> 2, wn = wid & 3;
  const int lanelo = lane & 15, laneq = lane >> 4;

  f32x4 acc[8][4] = {};
  // pass 1: logvar GEMM
  gemm256_acc(Av + (size_t)m0 * 2048, 2048, Btv + (size_t)n0 * 2048, 2048, 32,
              lds, acc);
  // in-register reparam transform: acc = eps*exp(0.5*(acc+bv2)) + bm2
#pragma unroll
  for (int nf = 0; nf < 4; ++nf) {
    const int d = n0 + wn * 64 + nf * 16 + lanelo;
    const float bvd = bvb[d];
    const float bmd = bmb[d];
#pragma unroll
    for (int mf = 0; mf < 8; ++mf)
#pragma unroll
      for (int r = 0; r < 4; ++r) {
        const int m = m0 + wm * 128 + mf * 16 + laneq * 4 + r;
        const float ev = eps[(size_t)m * 8192 + e * 1024 + d];
        acc[mf][nf][r] = ev * __expf(0.5f * (acc[mf][nf][r] + bvd)) + bmd;
      }
  }
  asm volatile("s_barrier" ::: "memory");
  // pass 2: mu GEMM, accumulating on top
  gemm256_acc(Am + (size_t)m0 * 2048, 2048, Btm + (size_t)n0 * 2048, 2048, 32,
              lds, acc);
  // epilogue: out += w * (mu + eps*exp(0.5*lv)), one atomic per element
#pragma unroll
  for (int mf = 0; mf < 8; ++mf)
#pragma unroll
    for (int r = 0; r < 4; ++r) {
      const int m = m0 + wm * 128 + mf * 16 + laneq * 4 + r;
      const float wgt = w[(size_t)m * 8 + e];
      float* orow = out + (size_t)m * 1024;
#pragma unroll
      for (int nf = 0; nf < 4; ++nf) {
        const int d = n0 + wn * 64 + nf * 16 + lanelo;
        unsafeAtomicAdd(&orow[d], wgt * acc[mf][nf][r]);
      }
    }
}

// ---- gate finish ----------------------------------------------------------
__global__ __launch_bounds__(256) void gate_finish_kernel(
    const float* __restrict__ hg, const float* __restrict__ Wg2,
    const float* __restrict__ bg2, const float* __restrict__ gu,
    float* __restrict__ w) {
  const int lane = threadIdx.x & 63, wid = threadIdx.x >> 6;
  const int row = blockIdx.x * 4 + wid;
  const float* hrow = hg + (size_t)row * 2048;
  float acc[8] = {0.f, 0.f, 0.f, 0.f, 0.f, 0.f, 0.f, 0.f};
  for (int h = lane; h < 2048; h += 64) {
    const float hv = hrow[h];
    const float* wr = Wg2 + (size_t)h * 8;
#pragma unroll
    for (int e = 0; e < 8; ++e) acc[e] += hv * wr[e];
  }
#pragma unroll
  for (int off = 32; off > 0; off >>= 1) {
#pragma unroll
    for (int e = 0; e < 8; ++e) acc[e] += __shfl_down(acc[e], off);
  }
  if (lane == 0) {
    float z[8], zmax = -1e30f;
#pragma unroll
    for (int e = 0; e < 8; ++e) {
      const float u = gu[(size_t)row * 8 + e];
      const float g = -logf(-logf(u));
      z[e] = (acc[e] + bg2[e] + g) / 0.1f;
      zmax = fmaxf(zmax, z[e]);
    }
    float s = 0.f;
#pragma unroll
    for (int e = 0; e < 8; ++e) {
      z[e] = __expf(z[e] - zmax);
      s += z[e];
    }
    const float inv = 1.f / s;
#pragma unroll
    for (int e = 0; e < 8; ++e) w[(size_t)row * 8 + e] = z[e] * inv;
  }
}

// ---------------------------------------------------------------------------

extern "C" void kernel_launch(void* const* d_in, const int* in_sizes, int n_in,
                              void* d_out, int out_size, void* d_ws,
                              size_t ws_size, hipStream_t stream) {
  const float* x = (const float*)d_in[0];
  const float* gu = (const float*)d_in[1];
  const float* eps = (const float*)d_in[2];
  const float* Wg1 = (const float*)d_in[3];
  const float* bg1 = (const float*)d_in[4];
  const float* Wg2 = (const float*)d_in[5];
  const float* bg2 = (const float*)d_in[6];
  const float* Wm1 = (const float*)d_in[7];
  const float* bm1 = (const float*)d_in[8];
  const float* Wm2 = (const float*)d_in[9];
  const float* bm2 = (const float*)d_in[10];
  const float* Wv1 = (const float*)d_in[11];
  const float* bv1 = (const float*)d_in[12];
  const float* Wv2 = (const float*)d_in[13];
  const float* bv2 = (const float*)d_in[14];
  float* out = (float*)d_out;

  static bool attr_done = false;
  if (!attr_done) {
    (void)hipFuncSetAttribute((const void*)gate_gemm1_256,
                              hipFuncAttributeMaxDynamicSharedMemorySize,
                              131072);
    (void)hipFuncSetAttribute((const void*)expert_gemm1_256,
                              hipFuncAttributeMaxDynamicSharedMemorySize,
                              131072);
    (void)hipFuncSetAttribute((const void*)gemm2_combine_256,
                              hipFuncAttributeMaxDynamicSharedMemorySize,
                              131072);
    attr_done = true;
  }

  char* ws = (char*)d_ws;
  size_t off = 0;
  auto alloc = [&](size_t bytes) -> void* {
    void* p = ws + off;
    off = (off + bytes + 255) & ~(size_t)255;
    return p;
  };
  _Float16* Ax = (_Float16*)alloc(4096UL * 3072 * 2);        // 24 MB
  _Float16* Wg1t = (_Float16*)alloc(2048UL * 3072 * 2);      // 12 MB
  _Float16* W1t = (_Float16*)alloc(16UL * 2048 * 1024 * 2);  // 64 MB
  _Float16* W2t = (_Float16*)alloc(16UL * 1024 * 2048 * 2);  // 64 MB
  float* hg = (float*)alloc(4096UL * 2048 * 4);              // 32 MB
  float* wbuf = (float*)alloc(4096UL * 8 * 4);
  _Float16* hm = (_Float16*)alloc(8UL * 4096 * 2048 * 2);    // 128 MB
  _Float16* hv = (_Float16*)alloc(8UL * 4096 * 2048 * 2);    // 128 MB

  // 1) conversions + out zero-init
  zero_out_kernel<<<4096, 256, 0, stream>>>((float4*)out);
  split_x_kernel<<<4096 * 1024 / 256, 256, 0, stream>>>(x, Ax);
  split_transpose_wg1_kernel<<<dim3(2048 / 64, 1024 / 64), 256, 0, stream>>>(Wg1, Wg1t);
  transpose_f32_to_f16<<<dim3(2048 / 64, 1024 / 64, 8), 256, 0, stream>>>(
      Wm1, W1t, 1024, 2048);
  transpose_f32_to_f16<<<dim3(2048 / 64, 1024 / 64, 8), 256, 0, stream>>>(
      Wv1, W1t + 8UL * 2048 * 1024, 1024, 2048);
  transpose_f32_to_f16<<<dim3(1024 / 64, 2048 / 64, 8), 256, 0, stream>>>(
      Wm2, W2t, 2048, 1024);
  transpose_f32_to_f16<<<dim3(1024 / 64, 2048 / 64, 8), 256, 0, stream>>>(
      Wv2, W2t + 8UL * 1024 * 2048, 2048, 1024);

  // 2) gate
  gate_gemm1_256<<<dim3(2048 / 256, 4096 / 256), 512, 131072, stream>>>(
      Ax, Wg1t, hg, bg1);
  gate_finish_kernel<<<4096 / 4, 256, 0, stream>>>(hg, Wg2, bg2, gu, wbuf);

  // 3) experts
  expert_gemm1_256<<<dim3(2048 / 256, 4096 / 256, 16), 512, 131072, stream>>>(
      Ax, W1t, hm, hv, bm1, bv1);
  gemm2_combine_256<<<dim3(1024 / 256, 4096 / 256, 8), 512, 131072, stream>>>(
      hm, hv, W2t, bm2, bv2, eps, wbuf, out);
}